// Round 2
// baseline (236.704 us; speedup 1.0000x reference)
//
#include <hip/hip_runtime.h>

// 16-qubit statevector, iSWAP(t) on qubits (3,7), qubit 0 = MSB.
// bit positions: qubit 3 -> bit 12, qubit 7 -> bit 8.
constexpr int DIM    = 1 << 16;    // 65536
constexpr int BATCH  = 256;        // f32 per row; 64 float4
constexpr int COLS   = BATCH / 4;  // 64 float4 columns per row
constexpr int BIT_HI = 1 << 12;    // qubit 3
constexpr int BIT_LO = 1 << 8;     // qubit 7
constexpr int MASK_BOTH = BIT_HI | BIT_LO;  // 0x1100

// Fused-quadrant decomposition: one thread handles one float4 column of all
// four rows {b12,b8} = {00,01,10,11} of TWO groups (hand-unrolled x2).
// 16384 groups x 64 cols, 2 groups/thread -> 524288 threads, 2048 blocks.
constexpr int NGROUP   = DIM / 4;          // 16384
constexpr int PSPLIT   = NGROUP / 2;       // 8192: thread does p and p+8192
constexpr int NTHREADS = PSPLIT * COLS;    // 524288
constexpr int NBLOCKS  = NTHREADS / 256;   // 2048 (~8 blocks/CU)

typedef float v4f __attribute__((ext_vector_type(4)));

// Insert 14 low bits of b into positions {0..7, 9..11, 13..15}
// (leaves bits 8 and 12 zero).
__device__ __forceinline__ int expand14(int b) {
    return (b & 0x00FF) | ((b & 0x0700) << 1) | ((b & 0x3800) << 2);
}

__global__ __launch_bounds__(256) void iswap_kernel(
    const float* __restrict__ sr, const float* __restrict__ si,
    const float* __restrict__ tp, float* __restrict__ out)
{
    const int gid = blockIdx.x * blockDim.x + threadIdx.x;   // [0, NTHREADS)
    float* __restrict__ out_r = out;
    float* __restrict__ out_i = out + (size_t)DIM * BATCH;

    // Fast trig: t in [0, 2pi), absmax threshold 0.0156 -> __sinf/__cosf fine.
    const float tv = tp[0];
    const float s = __sinf(tv);
    const float c = __cosf(tv);

    const int col = gid & (COLS - 1);
    const int p0  = gid >> 6;              // [0, PSPLIT)
    const int p1  = p0 + PSPLIT;

    // All offsets < 2^24 floats -> 32-bit arithmetic, saddr+voffset friendly.
    const int b0  = expand14(p0) * BATCH + col * 4;   // group 0, b12=b8=0
    const int b1  = expand14(p1) * BATCH + col * 4;   // group 1
    constexpr int O01 = BIT_LO * BATCH;      // +  65536 floats
    constexpr int O10 = BIT_HI * BATCH;      // +1048576 floats
    constexpr int O11 = MASK_BOTH * BATCH;   // +1114112 floats

    // Plain cached loads/stores — matches the 6.29 TB/s float4-copy pattern.
    // (Poison fills between iterations evict L2/L3 anyway; NT buys nothing
    // on reads and evict-first stores can hurt write-combining.)
    // Issue all 16 loads first: 256 B/lane outstanding.
    const v4f r01a = *(const v4f*)(sr + b0 + O01);
    const v4f m01a = *(const v4f*)(si + b0 + O01);
    const v4f r10a = *(const v4f*)(sr + b0 + O10);
    const v4f m10a = *(const v4f*)(si + b0 + O10);
    const v4f r01b = *(const v4f*)(sr + b1 + O01);
    const v4f m01b = *(const v4f*)(si + b1 + O01);
    const v4f r10b = *(const v4f*)(sr + b1 + O10);
    const v4f m10b = *(const v4f*)(si + b1 + O10);
    const v4f r00a = *(const v4f*)(sr + b0);
    const v4f m00a = *(const v4f*)(si + b0);
    const v4f r11a = *(const v4f*)(sr + b0 + O11);
    const v4f m11a = *(const v4f*)(si + b0 + O11);
    const v4f r00b = *(const v4f*)(sr + b1);
    const v4f m00b = *(const v4f*)(si + b1);
    const v4f r11b = *(const v4f*)(sr + b1 + O11);
    const v4f m11b = *(const v4f*)(si + b1 + O11);

    // new01 = c*old01 - i*s*old10 ; new10 = c*old10 - i*s*old01
    // re(new01) = c*r01 + s*m10 ; im(new01) = c*m01 - s*r10  (sym. for 10)
    const v4f nr01a = c * r01a + s * m10a;
    const v4f ni01a = c * m01a - s * r10a;
    const v4f nr10a = c * r10a + s * m01a;
    const v4f ni10a = c * m10a - s * r01a;
    const v4f nr01b = c * r01b + s * m10b;
    const v4f ni01b = c * m01b - s * r10b;
    const v4f nr10b = c * r10b + s * m01b;
    const v4f ni10b = c * m10b - s * r01b;

    *(v4f*)(out_r + b0 + O01) = nr01a;
    *(v4f*)(out_i + b0 + O01) = ni01a;
    *(v4f*)(out_r + b0 + O10) = nr10a;
    *(v4f*)(out_i + b0 + O10) = ni10a;
    *(v4f*)(out_r + b1 + O01) = nr01b;
    *(v4f*)(out_i + b1 + O01) = ni01b;
    *(v4f*)(out_r + b1 + O10) = nr10b;
    *(v4f*)(out_i + b1 + O10) = ni10b;
    *(v4f*)(out_r + b0)       = r00a;
    *(v4f*)(out_i + b0)       = m00a;
    *(v4f*)(out_r + b0 + O11) = r11a;
    *(v4f*)(out_i + b0 + O11) = m11a;
    *(v4f*)(out_r + b1)       = r00b;
    *(v4f*)(out_i + b1)       = m00b;
    *(v4f*)(out_r + b1 + O11) = r11b;
    *(v4f*)(out_i + b1 + O11) = m11b;
}

extern "C" void kernel_launch(void* const* d_in, const int* in_sizes, int n_in,
                              void* d_out, int out_size, void* d_ws, size_t ws_size,
                              hipStream_t stream) {
    const float* sr = (const float*)d_in[0];
    const float* si = (const float*)d_in[1];
    const float* t  = (const float*)d_in[2];
    float* out = (float*)d_out;

    static_assert(NTHREADS % 256 == 0, "grid sizing");
    iswap_kernel<<<dim3(NBLOCKS), dim3(256), 0, stream>>>(sr, si, t, out);
}

// Round 4
// 232.009 us; speedup vs baseline: 1.0202x; 1.0202x over previous
//
#include <hip/hip_runtime.h>

// 16-qubit statevector, iSWAP(t) on qubits (3,7), qubit 0 = MSB.
// bit positions: qubit 3 -> bit 12, qubit 7 -> bit 8.
constexpr int DIM    = 1 << 16;    // 65536
constexpr int BATCH  = 256;        // f32 per row; 64 float4
constexpr int COLS   = BATCH / 4;  // 64 float4 columns per row
constexpr int BIT_HI = 1 << 12;    // qubit 3
constexpr int BIT_LO = 1 << 8;     // qubit 7
constexpr int MASK_BOTH = BIT_HI | BIT_LO;  // 0x1100

// Fused-quadrant decomposition: one thread handles one float4 column of all
// four rows {b12,b8} = {00,01,10,11} of TWO groups (hand-unrolled x2).
// 16384 groups x 64 cols, 2 groups/thread -> 524288 threads, 2048 blocks.
constexpr int NGROUP   = DIM / 4;          // 16384
constexpr int PSPLIT   = NGROUP / 2;       // 8192: thread does p and p+8192
constexpr int NTHREADS = PSPLIT * COLS;    // 524288
constexpr int NBLOCKS  = NTHREADS / 256;   // 2048 (~8 blocks/CU)

typedef float v4f __attribute__((ext_vector_type(4)));

// Insert 14 low bits of b into positions {0..7, 9..11, 13..15}
// (leaves bits 8 and 12 zero).
__device__ __forceinline__ int expand14(int b) {
    return (b & 0x00FF) | ((b & 0x0700) << 1) | ((b & 0x3800) << 2);
}

__global__ __launch_bounds__(256) void iswap_kernel(
    const float* __restrict__ sr, const float* __restrict__ si,
    const float* __restrict__ tp, float* __restrict__ out)
{
    const int gid = blockIdx.x * blockDim.x + threadIdx.x;   // [0, NTHREADS)
    float* __restrict__ out_r = out;
    float* __restrict__ out_i = out + (size_t)DIM * BATCH;

    // Fast trig: t in [0, 2pi), absmax threshold 0.0156 -> __sinf/__cosf fine.
    const float tv = tp[0];
    const float s = __sinf(tv);
    const float c = __cosf(tv);

    const int col = gid & (COLS - 1);
    const int p0  = gid >> 6;              // [0, PSPLIT)
    const int p1  = p0 + PSPLIT;

    // All offsets < 2^24 floats -> 32-bit arithmetic, saddr+voffset friendly.
    const int b0  = expand14(p0) * BATCH + col * 4;   // group 0, b12=b8=0
    const int b1  = expand14(p1) * BATCH + col * 4;   // group 1
    constexpr int O01 = BIT_LO * BATCH;      // +  65536 floats
    constexpr int O10 = BIT_HI * BATCH;      // +1048576 floats
    constexpr int O11 = MASK_BOTH * BATCH;   // +1114112 floats

    // Nontemporal everywhere: 268 MB stream with zero reuse — evict-first
    // avoids L2 write-allocate churn (R2 showed cached = +9 us regression).
    // Issue all 16 loads first: 256 B/lane outstanding (deep MLP).
    const v4f r01a = __builtin_nontemporal_load((const v4f*)(sr + b0 + O01));
    const v4f m01a = __builtin_nontemporal_load((const v4f*)(si + b0 + O01));
    const v4f r10a = __builtin_nontemporal_load((const v4f*)(sr + b0 + O10));
    const v4f m10a = __builtin_nontemporal_load((const v4f*)(si + b0 + O10));
    const v4f r01b = __builtin_nontemporal_load((const v4f*)(sr + b1 + O01));
    const v4f m01b = __builtin_nontemporal_load((const v4f*)(si + b1 + O01));
    const v4f r10b = __builtin_nontemporal_load((const v4f*)(sr + b1 + O10));
    const v4f m10b = __builtin_nontemporal_load((const v4f*)(si + b1 + O10));
    const v4f r00a = __builtin_nontemporal_load((const v4f*)(sr + b0));
    const v4f m00a = __builtin_nontemporal_load((const v4f*)(si + b0));
    const v4f r11a = __builtin_nontemporal_load((const v4f*)(sr + b0 + O11));
    const v4f m11a = __builtin_nontemporal_load((const v4f*)(si + b0 + O11));
    const v4f r00b = __builtin_nontemporal_load((const v4f*)(sr + b1));
    const v4f m00b = __builtin_nontemporal_load((const v4f*)(si + b1));
    const v4f r11b = __builtin_nontemporal_load((const v4f*)(sr + b1 + O11));
    const v4f m11b = __builtin_nontemporal_load((const v4f*)(si + b1 + O11));

    // new01 = c*old01 - i*s*old10 ; new10 = c*old10 - i*s*old01
    // re(new01) = c*r01 + s*m10 ; im(new01) = c*m01 - s*r10  (sym. for 10)
    const v4f nr01a = c * r01a + s * m10a;
    const v4f ni01a = c * m01a - s * r10a;
    const v4f nr10a = c * r10a + s * m01a;
    const v4f ni10a = c * m10a - s * r01a;
    const v4f nr01b = c * r01b + s * m10b;
    const v4f ni01b = c * m01b - s * r10b;
    const v4f nr10b = c * r10b + s * m01b;
    const v4f ni10b = c * m10b - s * r01b;

    __builtin_nontemporal_store(nr01a, (v4f*)(out_r + b0 + O01));
    __builtin_nontemporal_store(ni01a, (v4f*)(out_i + b0 + O01));
    __builtin_nontemporal_store(nr10a, (v4f*)(out_r + b0 + O10));
    __builtin_nontemporal_store(ni10a, (v4f*)(out_i + b0 + O10));
    __builtin_nontemporal_store(nr01b, (v4f*)(out_r + b1 + O01));
    __builtin_nontemporal_store(ni01b, (v4f*)(out_i + b1 + O01));
    __builtin_nontemporal_store(nr10b, (v4f*)(out_r + b1 + O10));
    __builtin_nontemporal_store(ni10b, (v4f*)(out_i + b1 + O10));
    __builtin_nontemporal_store(r00a,  (v4f*)(out_r + b0));
    __builtin_nontemporal_store(m00a,  (v4f*)(out_i + b0));
    __builtin_nontemporal_store(r11a,  (v4f*)(out_r + b0 + O11));
    __builtin_nontemporal_store(m11a,  (v4f*)(out_i + b0 + O11));
    __builtin_nontemporal_store(r00b,  (v4f*)(out_r + b1));
    __builtin_nontemporal_store(m00b,  (v4f*)(out_i + b1));
    __builtin_nontemporal_store(r11b,  (v4f*)(out_r + b1 + O11));
    __builtin_nontemporal_store(m11b,  (v4f*)(out_i + b1 + O11));
}

extern "C" void kernel_launch(void* const* d_in, const int* in_sizes, int n_in,
                              void* d_out, int out_size, void* d_ws, size_t ws_size,
                              hipStream_t stream) {
    const float* sr = (const float*)d_in[0];
    const float* si = (const float*)d_in[1];
    const float* t  = (const float*)d_in[2];
    float* out = (float*)d_out;

    static_assert(NTHREADS % 256 == 0, "grid sizing");
    iswap_kernel<<<dim3(NBLOCKS), dim3(256), 0, stream>>>(sr, si, t, out);
}